// Round 1
// baseline (724.641 us; speedup 1.0000x reference)
//
#include <hip/hip_runtime.h>
#include <math.h>

// Problem constants (match reference)
#define N_ROWS 8192
#define ALPHA 40.0f
#define BETA 2.0f
#define MARGIN 0.5f

#define TPB 256
#define VPT (N_ROWS / (TPB * 4))   // float4 chunks per thread = 8

__global__ __launch_bounds__(TPB) void binomial_loss_kernel(
    const float* __restrict__ sim,
    const int*   __restrict__ targets,
    float* __restrict__ out_loss,
    float* __restrict__ out_grad)
{
    const int row  = blockIdx.x;
    const int t    = threadIdx.x;
    const int tRow = targets[row];

    const float4* row4 = reinterpret_cast<const float4*>(sim + (size_t)row * N_ROWS);
    const int4*   tg4  = reinterpret_cast<const int4*>(targets);

    // ---- Pass A: stage row in registers, build same-mask, count pos/neg ----
    float4 v[VPT];
    unsigned int sameMask[VPT];
    int posC = 0;   // same-label pairs with sim < 1
    int sameC = 0;  // same-label pairs (incl. diagonal)

    #pragma unroll
    for (int k = 0; k < VPT; ++k) {
        const int idx = t + k * TPB;
        v[k] = row4[idx];
        const int4 tg = tg4[idx];
        const float* vf = reinterpret_cast<const float*>(&v[k]);
        const int tgv[4] = {tg.x, tg.y, tg.z, tg.w};
        unsigned m = 0;
        #pragma unroll
        for (int j = 0; j < 4; ++j) {
            const bool same = (tgv[j] == tRow);
            m |= (same ? (1u << j) : 0u);
            sameC += same ? 1 : 0;
            posC  += (same && vf[j] < 1.0f) ? 1 : 0;
        }
        sameMask[k] = m;
    }

    // ---- Block reduction of counts (wave shfl, then tiny LDS) ----
    #pragma unroll
    for (int off = 32; off > 0; off >>= 1) {
        posC  += __shfl_down(posC,  off, 64);
        sameC += __shfl_down(sameC, off, 64);
    }
    __shared__ int sPos[TPB / 64];
    __shared__ int sSame[TPB / 64];
    __shared__ float sPosInv, sNegInv, sValid;
    const int wave = t >> 6, lane = t & 63;
    if (lane == 0) { sPos[wave] = posC; sSame[wave] = sameC; }
    __syncthreads();
    if (t == 0) {
        int p = 0, sm = 0;
        #pragma unroll
        for (int w = 0; w < TPB / 64; ++w) { p += sPos[w]; sm += sSame[w]; }
        const int negRaw = N_ROWS - sm;
        sValid  = (negRaw > 0) ? 1.0f : 0.0f;
        sPosInv = 1.0f / (float)((p      > 0) ? p      : 1);
        sNegInv = 1.0f / (float)((negRaw > 0) ? negRaw : 1);
    }
    __syncthreads();
    const float posInv = sPosInv;
    const float negInv = sNegInv;
    const float valid  = sValid;

    // ---- Pass B: compute loss/grad from registers, coalesced float4 stores --
    float4* outL4 = reinterpret_cast<float4*>(out_loss + (size_t)row * N_ROWS);
    float4* outG4 = reinterpret_cast<float4*>(out_grad + (size_t)row * N_ROWS);

    #pragma unroll
    for (int k = 0; k < VPT; ++k) {
        float4 L, G;
        const float* vf = reinterpret_cast<const float*>(&v[k]);
        float* lf = reinterpret_cast<float*>(&L);
        float* gf = reinterpret_cast<float*>(&G);
        const unsigned m = sameMask[k];
        #pragma unroll
        for (int j = 0; j < 4; ++j) {
            const float sv   = vf[j];
            const float s    = sv - MARGIN;
            const bool  same = ((m >> j) & 1u) != 0u;
            // x = (same ? -BETA : ALPHA) * s ; shared exp for softplus+sigmoid
            const float x  = (same ? -BETA : ALPHA) * s;
            const float e  = __expf(-fabsf(x));        // exp(-|x|), never overflows
            const float sp = fmaxf(x, 0.0f) + log1pf(e);
            const float sg = ((x >= 0.0f) ? 1.0f : e) / (1.0f + e);
            const float coef = same ? -BETA : ALPHA;
            const float inv  = same ? posInv : negInv;
            // same && sim >= 1 -> masked out entirely; also apply row_valid
            const float keep = (same && sv >= 1.0f) ? 0.0f : valid;
            lf[j] = sp * keep;
            gf[j] = coef * sg * inv * keep;
        }
        outL4[t + k * TPB] = L;
        outG4[t + k * TPB] = G;
    }
}

extern "C" void kernel_launch(void* const* d_in, const int* in_sizes, int n_in,
                              void* d_out, int out_size, void* d_ws, size_t ws_size,
                              hipStream_t stream) {
    const float* sim     = (const float*)d_in[0];
    const int*   targets = (const int*)d_in[1];
    float* out_loss = (float*)d_out;
    float* out_grad = out_loss + (size_t)N_ROWS * N_ROWS;

    binomial_loss_kernel<<<N_ROWS, TPB, 0, stream>>>(sim, targets, out_loss, out_grad);
}